// Round 4
// baseline (326.232 us; speedup 1.0000x reference)
//
#include <hip/hip_runtime.h>

#define HH 512
#define WW 512
#define NB 4

// ---------------- Stage 1: 11x11 convs (1->8, pos & neg) + spike/WTA logic ----------------
#define K1 11
#define PAD1 5
#define T1 32
#define IN1 42        // 32 + 10 halo
#define S1 44         // LDS row stride (floats)

// VGPR need: accP+accN(64) + a/cc(32) + misc ~= 115 -> 4 waves/EU budget (<=128)
__global__ __launch_bounds__(256, 4) void stage1_kernel(
    const float* __restrict__ inp, const float* __restrict__ Wb,
    unsigned char* __restrict__ border)
{
    __shared__ __align__(16) float s0[IN1 * S1];
    __shared__ __align__(16) float s1[IN1 * S1];

    const int b   = blockIdx.z;
    const int tx0 = blockIdx.x * T1;
    const int ty0 = blockIdx.y * T1;
    const float* in0 = inp + ((size_t)b * 2 + 0) * (HH * WW);
    const float* in1 = inp + ((size_t)b * 2 + 1) * (HH * WW);

    for (int i = threadIdx.x; i < IN1 * IN1; i += 256) {
        int iy = i / IN1, ix = i - iy * IN1;
        int gy = ty0 + iy - PAD1, gx = tx0 + ix - PAD1;
        bool ok = (gy >= 0) & (gy < HH) & (gx >= 0) & (gx < WW);
        int idx = gy * WW + gx;
        s0[iy * S1 + ix] = ok ? in0[idx] : 0.f;
        s1[iy * S1 + ix] = ok ? in1[idx] : 0.f;
    }
    __syncthreads();

    const int lx = threadIdx.x & 7;   // 8 groups of 4 px -> 32 wide
    const int ly = threadIdx.x >> 3;  // 32 rows
    const int px = lx * 4;
    const int py = ly;

    float accP[8][4];
    float accN[8][4];
    #pragma unroll
    for (int c = 0; c < 8; c++)
        #pragma unroll
        for (int p = 0; p < 4; p++) { accP[c][p] = 0.f; accN[c][p] = 0.f; }

    #pragma unroll 1
    for (int ky = 0; ky < K1; ky++) {
        const float4* r0 = (const float4*)&s0[(py + ky) * S1 + px];
        const float4* r1 = (const float4*)&s1[(py + ky) * S1 + px];
        float a[16], cc[16];
        #pragma unroll
        for (int r = 0; r < 4; r++) {
            *(float4*)&a[4 * r]  = r0[r];
            *(float4*)&cc[4 * r] = r1[r];
        }
        #pragma unroll
        for (int c = 0; c < 8; c++) {
            const float* wr = Wb + c * (K1 * K1) + ky * K1;  // uniform -> s_load
            #pragma unroll
            for (int kx = 0; kx < K1; kx++) {
                const float wv = wr[kx];
                #pragma unroll
                for (int p = 0; p < 4; p++) {
                    accP[c][p] = fmaf(a[kx + p],  wv, accP[c][p]);
                    accN[c][p] = fmaf(cc[kx + p], wv, accN[c][p]);
                }
            }
        }
    }

    const int gy = ty0 + py;
    const int gxbase = tx0 + px;

    float chv[16][4];
    #pragma unroll
    for (int p = 0; p < 4; p++) {
        float vm = s0[(py + PAD1) * S1 + px + PAD1 + p]
                 + s1[(py + PAD1) * S1 + px + PAD1 + p];
        float pe[4], po[4], ne[4], no[4];
        #pragma unroll
        for (int o = 0; o < 4; o++) {
            pe[o] = (accP[2 * o][p]     >= 1.f) ? 1.f : 0.f;
            po[o] = (accP[2 * o + 1][p] >= 1.f) ? 1.f : 0.f;
            ne[o] = (accN[2 * o][p]     >= 1.f) ? 1.f : 0.f;
            no[o] = (accN[2 * o + 1][p] >= 1.f) ? 1.f : 0.f;
        }
        float b13[4], b24[4], tp[4];
        float mx = 0.f;
        #pragma unroll
        for (int o = 0; o < 4; o++) {
            float sa = (vm * (pe[o] - 1.5f * no[o]) >= 1.f) ? 1.f : 0.f;
            float sb = (vm * (ne[o] - 1.5f * po[o]) >= 1.f) ? 1.f : 0.f;
            b13[o] = sa + sb;
            float sc = (vm * (po[o] - 1.5f * ne[o]) >= 1.f) ? 1.f : 0.f;
            float sd = (vm * (no[o] - 1.5f * pe[o]) >= 1.f) ? 1.f : 0.f;
            b24[o] = sc + sd;
            tp[o] = fabsf(b13[o] - b24[o]);
            mx = fmaxf(mx, tp[o]);
        }
        #pragma unroll
        for (int o = 0; o < 4; o++) {
            float d   = b13[o] - b24[o];
            float wta = (tp[o] == mx) ? 1.f : 0.f;
            float b1p = (wta * d >= 1.f)    ? 1.f : 0.f;
            float b1n = (-(wta * d) >= 1.f) ? 1.f : 0.f;
            chv[4 * o + 0][p] = b1p * b13[o];
            chv[4 * o + 1][p] = b1p * b24[o];  // G_INH = 1.0
            chv[4 * o + 2][p] = b1n * b24[o];
            chv[4 * o + 3][p] = b1n * b13[o];  // G_INH = 1.0
        }
    }
    #pragma unroll
    for (int k = 0; k < 16; k++) {
        unsigned int w32 = (unsigned int)(unsigned char)chv[k][0]
                         | ((unsigned int)(unsigned char)chv[k][1] << 8)
                         | ((unsigned int)(unsigned char)chv[k][2] << 16)
                         | ((unsigned int)(unsigned char)chv[k][3] << 24);
        *(unsigned int*)&border[(((size_t)b * 16 + k) * HH + gy) * WW + gxbase] = w32;
    }
}

// ---------------- Stage 2: depthwise 23x23 conv, one (batch,channel) plane per block ------
// Tile 64x128 out, thread = 8x * 4y. Loop input rows; each staged row read once per thread
// and feeds 4 output-row accumulators. Weights via uniform (scalar) global loads.
#define K2 23
#define PAD2 11
#define T2X 64
#define T2Y 128
#define S2 88          // LDS cols: global x = tx0-12+col, col 0..87 (16B-aligned reads)
#define R2 150         // staged rows: ty0-11 .. ty0+138

// LDS 52.8 KB caps at 3 blocks/CU (=3 waves/EU) -> allow the matching VGPR budget (~170)
// so a[32]+acc[32] stay register-resident (round-3's VGPR=68 forced LDS re-reads per dy).
__global__ __launch_bounds__(256, 3) void stage2_kernel(
    const unsigned char* __restrict__ border, const float* __restrict__ Wg,
    unsigned char* __restrict__ gsp)
{
    __shared__ __align__(16) float tile[R2 * S2];   // 52.8 KB -> 3 blocks/CU

    const int z   = blockIdx.z;
    const int b   = z >> 4;
    const int c   = z & 15;
    const int tx0 = blockIdx.x * T2X;
    const int ty0 = blockIdx.y * T2Y;
    const unsigned char* bp = border + ((size_t)b * 16 + c) * (HH * WW);

    // ---- stage u8 -> f32 tile: rows ty0-11.., cols tx0-12.. (4-byte aligned groups) ----
    for (int i = threadIdx.x; i < R2 * (S2 / 4); i += 256) {
        int iy = i / (S2 / 4), c4 = i - iy * (S2 / 4);
        int gy  = ty0 - PAD2 + iy;
        int gx0 = tx0 - 12 + 4 * c4;
        float4 f;
        bool rowok = (unsigned)gy < HH;
        if (rowok & ((unsigned)gx0 < WW)) {      // gx0 % 4 == 0, so gx0<512 => gx0+3<512
            unsigned u = *(const unsigned*)(bp + (size_t)gy * WW + gx0);
            f.x = (float)(u & 255u);
            f.y = (float)((u >> 8) & 255u);
            f.z = (float)((u >> 16) & 255u);
            f.w = (float)(u >> 24);
        } else if (rowok) {
            const unsigned char* rowp = bp + (size_t)gy * WW;
            f.x = ((unsigned)(gx0 + 0) < WW) ? (float)rowp[gx0 + 0] : 0.f;
            f.y = ((unsigned)(gx0 + 1) < WW) ? (float)rowp[gx0 + 1] : 0.f;
            f.z = ((unsigned)(gx0 + 2) < WW) ? (float)rowp[gx0 + 2] : 0.f;
            f.w = ((unsigned)(gx0 + 3) < WW) ? (float)rowp[gx0 + 3] : 0.f;
        } else {
            f.x = f.y = f.z = f.w = 0.f;
        }
        *(float4*)&tile[iy * S2 + 4 * c4] = f;
    }
    __syncthreads();

    const int lx = threadIdx.x & 7;    // 8 x-groups of 8 px -> 64 wide
    const int ly = threadIdx.x >> 3;   // 32 y-groups of 4 rows -> 128 tall
    const int px = lx * 8;
    const int py = ly * 4;

    float acc[4][8];
    #pragma unroll
    for (int dy = 0; dy < 4; dy++)
        #pragma unroll
        for (int p = 0; p < 8; p++) acc[dy][p] = 0.f;

    const float* wc = Wg + c * (K2 * K2);

    #pragma unroll 1
    for (int t = 0; t < 26; t++) {
        // one row window, read once, feeds up to 4 accumulator rows
        const float4* rp = (const float4*)&tile[(py + t) * S2 + px];
        float a[32];
        #pragma unroll
        for (int r = 0; r < 8; r++) *(float4*)&a[4 * r] = rp[r];
        #pragma unroll
        for (int dy = 0; dy < 4; dy++) {
            const int ky = t - dy;
            if (ky >= 0 && ky < K2) {            // wave-uniform branch
                const float* wr = wc + ky * K2;  // uniform -> s_load
                #pragma unroll
                for (int kx = 0; kx < K2; kx++) {
                    const float wv = wr[kx];
                    #pragma unroll
                    for (int p = 0; p < 8; p++)
                        acc[dy][p] = fmaf(a[kx + p + 1], wv, acc[dy][p]);
                }
            }
        }
    }

    // ---- spike + write u8 plane ----
    const int ox = tx0 + px;
    unsigned char* gp = gsp + ((size_t)b * 16 + c) * (HH * WW);
    #pragma unroll
    for (int dy = 0; dy < 4; dy++) {
        const int oy = ty0 + py + dy;
        unsigned lo = 0, hi = 0;
        #pragma unroll
        for (int p = 0; p < 4; p++) lo |= (acc[dy][p]     >= 1.f ? 1u : 0u) << (8 * p);
        #pragma unroll
        for (int p = 0; p < 4; p++) hi |= (acc[dy][p + 4] >= 1.f ? 1u : 0u) << (8 * p);
        uint2 v; v.x = lo; v.y = hi;
        *(uint2*)&gp[(size_t)oy * WW + ox] = v;
    }
}

// ---------------- Stage 3: combine 16 spike planes -> output ----------------
__global__ __launch_bounds__(256) void combine_kernel(
    const unsigned char* __restrict__ gsp, float* __restrict__ out)
{
    const int idx = blockIdx.x * 256 + threadIdx.x;   // 0 .. 4*65536-1 (uint granules)
    const int b = idx >> 16;
    const int r = idx & 65535;
    const unsigned* g = (const unsigned*)gsp;
    const int pb = b * 16;
    unsigned s = 0;
    #pragma unroll
    for (int o = 0; o < 4; o++) {
        unsigned g0 = g[(size_t)(pb + 4 * o + 0) * 65536 + r];
        unsigned g1 = g[(size_t)(pb + 4 * o + 1) * 65536 + r];
        unsigned g2 = g[(size_t)(pb + 4 * o + 2) * 65536 + r];
        unsigned g3 = g[(size_t)(pb + 4 * o + 3) * 65536 + r];
        s += ((g0 & ~g1) & 0x01010101u) + ((g2 & ~g3) & 0x01010101u);
    }
    float4 f;
    f.x = (float)(s & 255u);
    f.y = (float)((s >> 8) & 255u);
    f.z = (float)((s >> 16) & 255u);
    f.w = (float)(s >> 24);
    ((float4*)out)[idx] = f;
}

extern "C" void kernel_launch(void* const* d_in, const int* in_sizes, int n_in,
                              void* d_out, int out_size, void* d_ws, size_t ws_size,
                              hipStream_t stream)
{
    const float* inp = (const float*)d_in[0];   // (4,2,512,512) f32
    const float* Wb  = (const float*)d_in[1];   // (8,1,11,11)   f32
    const float* Wg  = (const float*)d_in[2];   // (16,1,23,23)  f32
    unsigned char* border = (unsigned char*)d_ws;                       // 16.78 MB
    unsigned char* gsp    = border + (size_t)NB * 16 * HH * WW;         // +16.78 MB
    float* out = (float*)d_out;                 // (4,512,512)   f32

    dim3 blk(256);
    dim3 g1(WW / T1, HH / T1, NB);          // 16x16x4 = 1024 blocks
    stage1_kernel<<<g1, blk, 0, stream>>>(inp, Wb, border);
    dim3 g2(WW / T2X, HH / T2Y, NB * 16);   // 8x4x64 = 2048 blocks
    stage2_kernel<<<g2, blk, 0, stream>>>(border, Wg, gsp);
    dim3 g3((NB * HH * WW / 4) / 256);      // 1024 blocks
    combine_kernel<<<g3, blk, 0, stream>>>(gsp, out);
}